// Round 7
// baseline (257.381 us; speedup 1.0000x reference)
//
#include <hip/hip_runtime.h>
#include <math.h>

#define BB 16384      // B
#define CC 50         // clusters
#define KK 128        // top-K
#define DD 128        // feature dim
#define MM 12800      // CC*2*KK rows of F
#define NSPLIT 20     // column splits for sim_all
#define CPS (MM / NSPLIT)       // 640 cols per split
#define CGS_PER_SPLIT (CPS / 16)            // 40 column groups of 16
#define MAXCAND 2048
#define TCAND 0.97f
// F rows are pre-scaled by SQS = sqrt(2/ln2), so dot(F,F) = sim * 2/ln2 and
// exp(sim/TEMP) = exp2(dot) directly — no per-element multiply in the epilogue.
#define SQS 1.6986436f

// Tiled F layout (per hi/lo buffer): for each 16-row group g, each kc (32-K
// chunk), 64 granules of 16B stored lane-ordered => an MFMA fragment load is
// ONE contiguous 1KB wave load at  base + g*4096 + kc*1024 + lane*16.

typedef __bf16 bf16x8 __attribute__((ext_vector_type(8)));
typedef float f32x4 __attribute__((ext_vector_type(4)));

__device__ inline unsigned short f2bf(float x) {
  unsigned u = __float_as_uint(x);
  unsigned r = (u + 0x7fffu + ((u >> 16) & 1u)) >> 16;
  return (unsigned short)r;
}
__device__ inline float bf2f(unsigned short h) {
  return __uint_as_float(((unsigned)h) << 16);
}

// ---------------------------------------------------------------------------
// Kernel 1a: coalesced candidate collection (values >= TCAND).
// ---------------------------------------------------------------------------
__global__ void cand_kernel(const float* __restrict__ prob, int* __restrict__ candCnt,
                            int* __restrict__ candIdx, float* __restrict__ candVal) {
  const int n = blockIdx.x * 256 + threadIdx.x;
  if (n >= BB * CC) return;
  const float v = prob[n];
  if (v >= TCAND) {
    const int i = n / CC, c = n - i * CC;
    const int slot = atomicAdd(&candCnt[c], 1);
    if (slot < MAXCAND) {
      candIdx[c * MAXCAND + slot] = i;
      candVal[c * MAXCAND + slot] = v;
    }
  }
}

// ---------------------------------------------------------------------------
// Kernel 1b: per-cluster exact top-K (fast path in LDS; exact fallback).
// ---------------------------------------------------------------------------
__global__ void select_kernel(const float* __restrict__ prob,
                              const int* __restrict__ candCnt,
                              const int* __restrict__ candIdx,
                              const float* __restrict__ candVal,
                              int* __restrict__ topk) {
  __shared__ float vals[MAXCAND];
  __shared__ int   idxs[MAXCAND];
  __shared__ int hist[256];
  __shared__ int sChosen, sKrem, gtc, eqc;
  __shared__ int eqIdx[256];
  const int c = blockIdx.x, t = threadIdx.x;
  const int cnt = candCnt[c];

  if (cnt >= KK && cnt <= MAXCAND) {
    for (int j = t; j < cnt; j += 256) {
      vals[j] = candVal[c * MAXCAND + j];
      idxs[j] = candIdx[c * MAXCAND + j];
    }
    __syncthreads();
    unsigned prefix = 0;
    int krem = KK;
    for (int pass = 0; pass < 4; ++pass) {
      const int shift = 24 - pass * 8;
      hist[t] = 0;
      __syncthreads();
      for (int j = t; j < cnt; j += 256) {
        unsigned u = __float_as_uint(vals[j]);
        bool match = (pass == 0) || ((u >> (shift + 8)) == (prefix >> (shift + 8)));
        if (match) atomicAdd(&hist[(u >> shift) & 255], 1);
      }
      __syncthreads();
      if (t == 0) {
        int kr = krem, b = 255;
        for (; b > 0; --b) {
          if (kr > hist[b]) kr -= hist[b];
          else break;
        }
        sChosen = b; sKrem = kr;
      }
      __syncthreads();
      prefix |= ((unsigned)sChosen) << shift;
      krem = sKrem;
      __syncthreads();
    }
    const unsigned T = prefix;
    if (t == 0) { gtc = 0; eqc = 0; }
    __syncthreads();
    for (int j = t; j < cnt; j += 256) {
      unsigned u = __float_as_uint(vals[j]);
      if (u > T) {
        int pos = atomicAdd(&gtc, 1);
        topk[c * KK + pos] = idxs[j];
      } else if (u == T) {
        int e = atomicAdd(&eqc, 1);
        if (e < 256) eqIdx[e] = idxs[j];
      }
    }
    __syncthreads();
    if (t == 0) {
      int base = gtc;
      int ec = eqc < 256 ? eqc : 256;
      for (int j2 = 0; j2 < krem; ++j2) {
        int bi = -1, bv = 0x7fffffff;
        for (int q = 0; q < ec; ++q) {
          int v = eqIdx[q];
          if (v >= 0 && v < bv) { bv = v; bi = q; }
        }
        topk[c * KK + base + j2] = bv;
        eqIdx[bi] = -1;
      }
    }
  } else {
    unsigned prefix = 0;
    int krem = KK;
    for (int pass = 0; pass < 4; ++pass) {
      const int shift = 24 - pass * 8;
      hist[t] = 0;
      __syncthreads();
      for (int i = t; i < BB; i += 256) {
        unsigned u = __float_as_uint(prob[i * CC + c]);
        bool match = (pass == 0) || ((u >> (shift + 8)) == (prefix >> (shift + 8)));
        if (match) atomicAdd(&hist[(u >> shift) & 255], 1);
      }
      __syncthreads();
      if (t == 0) {
        int kr = krem, b = 255;
        for (; b > 0; --b) {
          if (kr > hist[b]) kr -= hist[b];
          else break;
        }
        sChosen = b; sKrem = kr;
      }
      __syncthreads();
      prefix |= ((unsigned)sChosen) << shift;
      krem = sKrem;
      __syncthreads();
    }
    const unsigned T = prefix;
    if (t == 0) { gtc = 0; eqc = 0; }
    __syncthreads();
    for (int i = t; i < BB; i += 256) {
      unsigned u = __float_as_uint(prob[i * CC + c]);
      if (u > T) {
        int pos = atomicAdd(&gtc, 1);
        topk[c * KK + pos] = i;
      } else if (u == T) {
        int e = atomicAdd(&eqc, 1);
        if (e < 256) eqIdx[e] = i;
      }
    }
    __syncthreads();
    if (t == 0) {
      int base = gtc;
      int ec = eqc < 256 ? eqc : 256;
      for (int j = 0; j < krem; ++j) {
        int bi = -1, bv = 0x7fffffff;
        for (int q = 0; q < ec; ++q) {
          int v = eqIdx[q];
          if (v >= 0 && v < bv) { bv = v; bi = q; }
        }
        topk[c * KK + base + j] = bv;
        eqIdx[bi] = -1;
      }
    }
  }
}

// ---------------------------------------------------------------------------
// Kernel 2: gather + L2-normalize + scale by SQS + hi/lo bf16 split, TILED.
// ---------------------------------------------------------------------------
__global__ void gather_norm(const float* __restrict__ zi, const float* __restrict__ zj,
                            const int* __restrict__ topk,
                            char* __restrict__ FhiT, char* __restrict__ FloT) {
  const int gw = (blockIdx.x * 256 + threadIdx.x) >> 6;
  const int lane = threadIdx.x & 63;
  if (gw >= MM) return;
  const int c = gw >> 8, p = gw & 255;
  const int idx = topk[c * KK + (p & (KK - 1))];
  const float* src = (p < KK ? zi : zj) + (size_t)idx * DD;
  float2 v = ((const float2*)src)[lane];
  float ss = fmaf(v.x, v.x, v.y * v.y);
#pragma unroll
  for (int m = 1; m < 64; m <<= 1) ss += __shfl_xor(ss, m, 64);
  const float scale = SQS / fmaxf(sqrtf(ss), 1e-8f);
  float a = v.x * scale, b = v.y * scale;
  unsigned short ah = f2bf(a), bh = f2bf(b);
  unsigned short al = f2bf(a - bf2f(ah)), bl = f2bf(b - bf2f(bh));
  unsigned hp = ((unsigned)bh << 16) | ah;
  unsigned lp = ((unsigned)bl << 16) | al;
  const size_t off = (size_t)(gw >> 4) * 4096 + (size_t)(lane >> 4) * 1024 +
                     (size_t)((((lane >> 2) & 3) * 16 + (gw & 15)) * 16 + (lane & 3) * 4);
  *(unsigned*)(FhiT + off) = hp;
  *(unsigned*)(FloT + off) = lp;
}

// ---------------------------------------------------------------------------
// Kernel 3: fused sim. OCCUPANCY RESTRUCTURE: each wave owns 32 rows (A regs
// halve to 64 VGPR), 4-wave blocks cover 128 rows, launch_bounds(256,3) ->
// 3 waves/SIMD. Phase-locked waves now stretch each other's MFMA bursts on
// the shared matrix pipe while epilogues hide underneath:
// util ~ 3*466/(3*466+E) vs round 6's ~1.5 waves/SIMD at 58%.
// Blocks [0, CC*2*NSPLIT): sum_all. Blocks [+0, +CC*4): own/pos sums.
// ---------------------------------------------------------------------------
__global__ __launch_bounds__(256, 3) void sim_fused_kernel(
    const char* __restrict__ FhiT, const char* __restrict__ FloT,
    float* __restrict__ part, float* __restrict__ ownArr, float* __restrict__ posArr) {
  const int tid = threadIdx.x;
  const int lane = tid & 63, wave = tid >> 6;
  const int lh = lane >> 4;
  const size_t laneoff = (size_t)lane * 16;

  if (blockIdx.x < CC * 2 * NSPLIT) {
    // ================= sum_all path =================
    const int c = blockIdx.x / (2 * NSPLIT);
    const int rem = blockIdx.x - c * (2 * NSPLIT);
    const int rb = rem / NSPLIT, split = rem - rb * NSPLIT;
    const int rowW = c * 256 + rb * 128 + wave * 32;
    const int cgBase = (split * CPS) >> 4;

    bf16x8 Ahi[2][4], Alo[2][4];
#pragma unroll
    for (int rg = 0; rg < 2; ++rg)
#pragma unroll
      for (int kc = 0; kc < 4; ++kc) {
        const size_t off = (size_t)((rowW >> 4) + rg) * 4096 + (size_t)kc * 1024 + laneoff;
        Ahi[rg][kc] = *(const bf16x8*)(FhiT + off);
        Alo[rg][kc] = *(const bf16x8*)(FloT + off);
      }

    bf16x8 bh[4], bl[4];
    f32x4 acc0[2], acc1[2];
    float sAll[8] = {0.f};

#define LOADB(IDX) do {                                                        \
      const size_t gb = (size_t)(cgBase + (IDX)) * 4096 + laneoff;             \
      _Pragma("unroll")                                                        \
      for (int kc = 0; kc < 4; ++kc) {                                         \
        bh[kc] = *(const bf16x8*)(FhiT + gb + kc * 1024);                      \
        bl[kc] = *(const bf16x8*)(FloT + gb + kc * 1024);                      \
      }                                                                        \
    } while (0)

#define MFMAB(ACC) do {                                                        \
      _Pragma("unroll")                                                        \
      for (int rg = 0; rg < 2; ++rg)                                           \
        ACC[rg] = __builtin_amdgcn_mfma_f32_16x16x32_bf16(                     \
            Ahi[rg][0], bh[0], (f32x4){0.f, 0.f, 0.f, 0.f}, 0, 0, 0);          \
      _Pragma("unroll")                                                        \
      for (int rg = 0; rg < 2; ++rg)                                           \
        ACC[rg] = __builtin_amdgcn_mfma_f32_16x16x32_bf16(Ahi[rg][0], bl[0], ACC[rg], 0, 0, 0); \
      _Pragma("unroll")                                                        \
      for (int rg = 0; rg < 2; ++rg)                                           \
        ACC[rg] = __builtin_amdgcn_mfma_f32_16x16x32_bf16(Alo[rg][0], bh[0], ACC[rg], 0, 0, 0); \
      _Pragma("unroll")                                                        \
      for (int kc = 1; kc < 4; ++kc) {                                         \
        _Pragma("unroll")                                                      \
        for (int rg = 0; rg < 2; ++rg)                                         \
          ACC[rg] = __builtin_amdgcn_mfma_f32_16x16x32_bf16(Ahi[rg][kc], bh[kc], ACC[rg], 0, 0, 0); \
        _Pragma("unroll")                                                      \
        for (int rg = 0; rg < 2; ++rg)                                         \
          ACC[rg] = __builtin_amdgcn_mfma_f32_16x16x32_bf16(Ahi[rg][kc], bl[kc], ACC[rg], 0, 0, 0); \
        _Pragma("unroll")                                                      \
        for (int rg = 0; rg < 2; ++rg)                                         \
          ACC[rg] = __builtin_amdgcn_mfma_f32_16x16x32_bf16(Alo[rg][kc], bh[kc], ACC[rg], 0, 0, 0); \
      }                                                                        \
    } while (0)

#define EXPSUM(ACC) do {                                                       \
      _Pragma("unroll")                                                        \
      for (int rg = 0; rg < 2; ++rg)                                           \
        _Pragma("unroll")                                                      \
        for (int q = 0; q < 4; ++q)                                            \
          sAll[rg * 4 + q] += __builtin_amdgcn_exp2f(ACC[rg][q]);              \
    } while (0)

    // pipeline: MFMA(cur) | load(next) | exp(prev), acc ping-pong
    LOADB(0);
    MFMAB(acc0);
    LOADB(1);
    for (int g = 1; g < CGS_PER_SPLIT - 1; g += 2) {
      MFMAB(acc1);
      LOADB(g + 1);
      EXPSUM(acc0);
      MFMAB(acc0);
      LOADB(g + 2);   // may read one group past split end: stays inside ws, unused
      EXPSUM(acc1);
    }
    MFMAB(acc1);      // group 39
    EXPSUM(acc0);
    EXPSUM(acc1);

#undef LOADB
#undef MFMAB
#undef EXPSUM

#pragma unroll
    for (int m = 1; m < 16; m <<= 1)
#pragma unroll
      for (int j = 0; j < 8; ++j) sAll[j] += __shfl_xor(sAll[j], m, 16);
    if ((lane & 15) == 0) {
#pragma unroll
      for (int rg = 0; rg < 2; ++rg)
#pragma unroll
        for (int i = 0; i < 4; ++i) {
          int row = rowW + rg * 16 + lh * 4 + i;
          part[(size_t)row * NSPLIT + split] = sAll[rg * 4 + i];
        }
    }
  } else {
    // ================= own/pos path =================
    const int bid2 = blockIdx.x - CC * 2 * NSPLIT;
    const int c = bid2 >> 2, q = bid2 & 3;
    const int rowW = c * 256 + q * 64 + wave * 16;
    const int cg0 = c * 16;

    bf16x8 Ahi[4], Alo[4];
#pragma unroll
    for (int kc = 0; kc < 4; ++kc) {
      const size_t off = (size_t)(rowW >> 4) * 4096 + (size_t)kc * 1024 + laneoff;
      Ahi[kc] = *(const bf16x8*)(FhiT + off);
      Alo[kc] = *(const bf16x8*)(FloT + off);
    }

    float sOwn[4] = {0.f}, sPos[4] = {0.f};
    for (int t = 0; t < 16; ++t) {
      const size_t gb = (size_t)(cg0 + t) * 4096 + laneoff;
      bf16x8 bh[4], bl[4];
#pragma unroll
      for (int kc = 0; kc < 4; ++kc) {
        bh[kc] = *(const bf16x8*)(FhiT + gb + kc * 1024);
        bl[kc] = *(const bf16x8*)(FloT + gb + kc * 1024);
      }
      f32x4 acc = {};
#pragma unroll
      for (int kc = 0; kc < 4; ++kc) {
        acc = __builtin_amdgcn_mfma_f32_16x16x32_bf16(Ahi[kc], bh[kc], acc, 0, 0, 0);
        acc = __builtin_amdgcn_mfma_f32_16x16x32_bf16(Ahi[kc], bl[kc], acc, 0, 0, 0);
        acc = __builtin_amdgcn_mfma_f32_16x16x32_bf16(Alo[kc], bh[kc], acc, 0, 0, 0);
      }
      const bool isPos = (t < 8);
#pragma unroll
      for (int i = 0; i < 4; ++i) {
        float e = __builtin_amdgcn_exp2f(acc[i]);
        sOwn[i] += e;
        if (isPos) sPos[i] += e;
      }
    }
#pragma unroll
    for (int m = 1; m < 16; m <<= 1)
#pragma unroll
      for (int i = 0; i < 4; ++i) {
        sOwn[i] += __shfl_xor(sOwn[i], m, 16);
        sPos[i] += __shfl_xor(sPos[i], m, 16);
      }
    if ((lane & 15) == 0) {
#pragma unroll
      for (int i = 0; i < 4; ++i) {
        int row = rowW + lh * 4 + i;
        ownArr[row] = sOwn[i];
        posArr[row] = sPos[i];
      }
    }
  }
}

// ---------------------------------------------------------------------------
// Kernel 4: per-row loss + in-block reduction -> 50 partial sums
// ---------------------------------------------------------------------------
__global__ void finalize_rows(const float* __restrict__ part,
                              const float* __restrict__ ownArr,
                              const float* __restrict__ posArr,
                              float* __restrict__ partial) {
  __shared__ float red[4];
  const int t = threadIdx.x;
  const int p = blockIdx.x * 256 + t;
  float a = 0.f;
#pragma unroll
  for (int sp = 0; sp < NSPLIT; ++sp) a += part[(size_t)p * NSPLIT + sp];
  float rl = logf(a - ownArr[p]) - logf(posArr[p]);
#pragma unroll
  for (int m = 1; m < 64; m <<= 1) rl += __shfl_xor(rl, m, 64);
  if ((t & 63) == 0) red[t >> 6] = rl;
  __syncthreads();
  if (t == 0) partial[blockIdx.x] = red[0] + red[1] + red[2] + red[3];
}

// ---------------------------------------------------------------------------
// Kernel 5: mean -> scalar (one wave over 50 partials)
// ---------------------------------------------------------------------------
__global__ void final_reduce(const float* __restrict__ partial, float* __restrict__ out) {
  const int t = threadIdx.x;   // 64 threads
  float s = (t < MM / 256) ? partial[t] : 0.f;
#pragma unroll
  for (int m = 1; m < 64; m <<= 1) s += __shfl_xor(s, m, 64);
  if (t == 0) out[0] = s * (1.0f / MM);
}

extern "C" void kernel_launch(void* const* d_in, const int* in_sizes, int n_in,
                              void* d_out, int out_size, void* d_ws, size_t ws_size,
                              hipStream_t stream) {
  const float* prob = (const float*)d_in[0];
  const float* zi   = (const float*)d_in[1];
  const float* zj   = (const float*)d_in[2];
  float* out = (float*)d_out;

  char* ws = (char*)d_ws;
  char* FhiT      = ws;                                              // 3,276,800 B
  char* FloT      = ws + 3276800;                                    // 3,276,800 B
  float* part     = (float*)(ws + 6553600);                          // 1,024,000 B
  float* ownArr   = (float*)(ws + 7577600);                          //    51,200 B
  float* posArr   = (float*)(ws + 7628800);                          //    51,200 B
  float* partial  = (float*)(ws + 7680000);                          //       256 B
  int*   topk     = (int*)  (ws + 7731200);                          //    25,600 B
  int*   candCnt  = (int*)  (ws + 7756800);                          //       256 B
  int*   candIdx  = (int*)  (ws + 7757056);                          //   409,600 B
  float* candVal  = (float*)(ws + 8166656);                          //   409,600 B

  hipMemsetAsync(candCnt, 0, 256, stream);
  cand_kernel     <<<(BB * CC + 255) / 256, 256, 0, stream>>>(prob, candCnt, candIdx, candVal);
  select_kernel   <<<CC, 256, 0, stream>>>(prob, candCnt, candIdx, candVal, topk);
  gather_norm     <<<MM / 4, 256, 0, stream>>>(zi, zj, topk, FhiT, FloT);
  sim_fused_kernel<<<CC * 2 * NSPLIT + CC * 4, 256, 0, stream>>>(FhiT, FloT, part, ownArr, posArr);
  finalize_rows   <<<MM / 256, 256, 0, stream>>>(part, ownArr, posArr, partial);
  final_reduce    <<<1, 64, 0, stream>>>(partial, out);
}

// Round 8
// 214.024 us; speedup vs baseline: 1.2026x; 1.2026x over previous
//
#include <hip/hip_runtime.h>
#include <math.h>

#define BB 16384      // B
#define CC 50         // clusters
#define KK 128        // top-K
#define DD 128        // feature dim
#define MM 12800      // CC*2*KK rows of F
#define NBLK 100      // 128-row blocks of F
#define NSYM 5050     // upper-triangular 128x128 tile pairs (incl. 100 diagonal)
#define MAXCAND 2048
#define TCAND 0.97f
// F rows are pre-scaled by SQS = sqrt(2/ln2): dot(F,F) = sim * 2/ln2, so
// exp(sim/TEMP) = exp2(dot) directly. Single bf16 product (no Ootomo split):
// dot err ~3e-4 -> final scalar err ~1e-6, far inside tolerance.
#define SQS 1.6986436f

// Tiled F layout: for each 32-row group G (400 groups), each kc (16-K chunk,
// 8 chunks), 64 granules of 16B lane-ordered for mfma_32x32x16_bf16 operands:
// granule(lane) = row G*32+(lane&31), k in kc*16 + (lane>>5)*8 .. +8.
// One fragment load = contiguous 1KB wave load at G*8192 + kc*1024 + lane*16.

typedef __bf16 bf16x8 __attribute__((ext_vector_type(8)));
typedef float f32x16 __attribute__((ext_vector_type(16)));

#define MFMA32(a, b, c) __builtin_amdgcn_mfma_f32_32x32x16_bf16(a, b, c, 0, 0, 0)

__device__ inline unsigned short f2bf(float x) {
  unsigned u = __float_as_uint(x);
  unsigned r = (u + 0x7fffu + ((u >> 16) & 1u)) >> 16;
  return (unsigned short)r;
}

// ---------------------------------------------------------------------------
// Kernel 1a: coalesced candidate collection (values >= TCAND).
// ---------------------------------------------------------------------------
__global__ void cand_kernel(const float* __restrict__ prob, int* __restrict__ candCnt,
                            int* __restrict__ candIdx, float* __restrict__ candVal) {
  const int n = blockIdx.x * 256 + threadIdx.x;
  if (n >= BB * CC) return;
  const float v = prob[n];
  if (v >= TCAND) {
    const int i = n / CC, c = n - i * CC;
    const int slot = atomicAdd(&candCnt[c], 1);
    if (slot < MAXCAND) {
      candIdx[c * MAXCAND + slot] = i;
      candVal[c * MAXCAND + slot] = v;
    }
  }
}

// ---------------------------------------------------------------------------
// Kernel 1b: per-cluster exact top-K (fast path in LDS; exact fallback).
// ---------------------------------------------------------------------------
__global__ void select_kernel(const float* __restrict__ prob,
                              const int* __restrict__ candCnt,
                              const int* __restrict__ candIdx,
                              const float* __restrict__ candVal,
                              int* __restrict__ topk) {
  __shared__ float vals[MAXCAND];
  __shared__ int   idxs[MAXCAND];
  __shared__ int hist[256];
  __shared__ int sChosen, sKrem, gtc, eqc;
  __shared__ int eqIdx[256];
  const int c = blockIdx.x, t = threadIdx.x;
  const int cnt = candCnt[c];

  if (cnt >= KK && cnt <= MAXCAND) {
    for (int j = t; j < cnt; j += 256) {
      vals[j] = candVal[c * MAXCAND + j];
      idxs[j] = candIdx[c * MAXCAND + j];
    }
    __syncthreads();
    unsigned prefix = 0;
    int krem = KK;
    for (int pass = 0; pass < 4; ++pass) {
      const int shift = 24 - pass * 8;
      hist[t] = 0;
      __syncthreads();
      for (int j = t; j < cnt; j += 256) {
        unsigned u = __float_as_uint(vals[j]);
        bool match = (pass == 0) || ((u >> (shift + 8)) == (prefix >> (shift + 8)));
        if (match) atomicAdd(&hist[(u >> shift) & 255], 1);
      }
      __syncthreads();
      if (t == 0) {
        int kr = krem, b = 255;
        for (; b > 0; --b) {
          if (kr > hist[b]) kr -= hist[b];
          else break;
        }
        sChosen = b; sKrem = kr;
      }
      __syncthreads();
      prefix |= ((unsigned)sChosen) << shift;
      krem = sKrem;
      __syncthreads();
    }
    const unsigned T = prefix;
    if (t == 0) { gtc = 0; eqc = 0; }
    __syncthreads();
    for (int j = t; j < cnt; j += 256) {
      unsigned u = __float_as_uint(vals[j]);
      if (u > T) {
        int pos = atomicAdd(&gtc, 1);
        topk[c * KK + pos] = idxs[j];
      } else if (u == T) {
        int e = atomicAdd(&eqc, 1);
        if (e < 256) eqIdx[e] = idxs[j];
      }
    }
    __syncthreads();
    if (t == 0) {
      int base = gtc;
      int ec = eqc < 256 ? eqc : 256;
      for (int j2 = 0; j2 < krem; ++j2) {
        int bi = -1, bv = 0x7fffffff;
        for (int q = 0; q < ec; ++q) {
          int v = eqIdx[q];
          if (v >= 0 && v < bv) { bv = v; bi = q; }
        }
        topk[c * KK + base + j2] = bv;
        eqIdx[bi] = -1;
      }
    }
  } else {
    unsigned prefix = 0;
    int krem = KK;
    for (int pass = 0; pass < 4; ++pass) {
      const int shift = 24 - pass * 8;
      hist[t] = 0;
      __syncthreads();
      for (int i = t; i < BB; i += 256) {
        unsigned u = __float_as_uint(prob[i * CC + c]);
        bool match = (pass == 0) || ((u >> (shift + 8)) == (prefix >> (shift + 8)));
        if (match) atomicAdd(&hist[(u >> shift) & 255], 1);
      }
      __syncthreads();
      if (t == 0) {
        int kr = krem, b = 255;
        for (; b > 0; --b) {
          if (kr > hist[b]) kr -= hist[b];
          else break;
        }
        sChosen = b; sKrem = kr;
      }
      __syncthreads();
      prefix |= ((unsigned)sChosen) << shift;
      krem = sKrem;
      __syncthreads();
    }
    const unsigned T = prefix;
    if (t == 0) { gtc = 0; eqc = 0; }
    __syncthreads();
    for (int i = t; i < BB; i += 256) {
      unsigned u = __float_as_uint(prob[i * CC + c]);
      if (u > T) {
        int pos = atomicAdd(&gtc, 1);
        topk[c * KK + pos] = i;
      } else if (u == T) {
        int e = atomicAdd(&eqc, 1);
        if (e < 256) eqIdx[e] = i;
      }
    }
    __syncthreads();
    if (t == 0) {
      int base = gtc;
      int ec = eqc < 256 ? eqc : 256;
      for (int j = 0; j < krem; ++j) {
        int bi = -1, bv = 0x7fffffff;
        for (int q = 0; q < ec; ++q) {
          int v = eqIdx[q];
          if (v >= 0 && v < bv) { bv = v; bi = q; }
        }
        topk[c * KK + base + j] = bv;
        eqIdx[bi] = -1;
      }
    }
  }
}

// ---------------------------------------------------------------------------
// Kernel 2: gather + L2-normalize + SQS scale + bf16, written in the tiled
// 32-row-group layout. One wave per row; lane holds features {2*lane, +1}.
// ---------------------------------------------------------------------------
__global__ void gather_norm(const float* __restrict__ zi, const float* __restrict__ zj,
                            const int* __restrict__ topk, char* __restrict__ FT) {
  const int gw = (blockIdx.x * 256 + threadIdx.x) >> 6;
  const int lane = threadIdx.x & 63;
  if (gw >= MM) return;
  const int c = gw >> 8, p = gw & 255;
  const int idx = topk[c * KK + (p & (KK - 1))];
  const float* src = (p < KK ? zi : zj) + (size_t)idx * DD;
  float2 v = ((const float2*)src)[lane];
  float ss = fmaf(v.x, v.x, v.y * v.y);
#pragma unroll
  for (int m = 1; m < 64; m <<= 1) ss += __shfl_xor(ss, m, 64);
  const float scale = SQS / fmaxf(sqrtf(ss), 1e-8f);
  unsigned short ah = f2bf(v.x * scale), bh = f2bf(v.y * scale);
  unsigned hp = ((unsigned)bh << 16) | ah;
  const int k2 = 2 * lane;
  const int kc = k2 >> 4;          // 16-K chunk
  const int kk = k2 & 15;
  const size_t off = (size_t)(gw >> 5) * 8192 + (size_t)kc * 1024 +
                     (size_t)(((kk >> 3) * 32 + (gw & 31)) * 16 + (kk & 7) * 2);
  *(unsigned*)(FT + off) = hp;
}

// ---------------------------------------------------------------------------
// Kernel 3: symmetric fused sim. Blocks [0,NSYM): upper-tri 128x128 tile
// (I,J). Row-sums of exp -> part[J][rows of I]; col-sums (mirror rows, since
// exp(S) symmetric) -> part[I][cols of J] (skipped on diagonal). Each part
// slot written exactly once -> deterministic, no atomics. 2 waves x 64 rows,
// 32x32x16 MFMA, acc ping-pong with the previous tile's exp2 interleaved
// per-kc between MFMAs. Blocks [NSYM, NSYM+100): own/pos row sums.
// ---------------------------------------------------------------------------
__global__ __launch_bounds__(128, 2) void sim_sym_kernel(
    const char* __restrict__ F, float* __restrict__ part,
    float* __restrict__ ownArr, float* __restrict__ posArr) {
  __shared__ float colLds[256];
  const int tid = threadIdx.x;
  const int lane = tid & 63, wave = tid >> 6;
  const int lh2 = lane >> 5;
  const size_t lo16 = (size_t)lane * 16;

  f32x16 Z = {};

#define LOADB(BUF, GIDX) {                                                     \
    _Pragma("unroll")                                                          \
    for (int kc = 0; kc < 8; ++kc)                                             \
      BUF[kc] = *(const bf16x8*)(F + (size_t)(GIDX) * 8192 + kc * 1024 + lo16);\
  }

  if (blockIdx.x < NSYM) {
    // ---- map linear tile id -> (I, J), J >= I, N=100 ----
    const int k = blockIdx.x;
    int I = (int)((201.0f - sqrtf(40401.0f - 8.0f * (float)k)) * 0.5f);
    while ((I + 1) * NBLK - ((I + 1) * I) / 2 <= k) ++I;
    while (I * NBLK - (I * (I - 1)) / 2 > k) --I;
    const int J = I + (k - (I * NBLK - (I * (I - 1)) / 2));
    const bool diag = (I == J);
    const int Ga = I * 4 + wave * 2;   // two 32-row groups per wave
    const int Gb = J * 4;

    bf16x8 A0[8], A1[8];
#pragma unroll
    for (int kc = 0; kc < 8; ++kc) {
      A0[kc] = *(const bf16x8*)(F + (size_t)Ga * 8192 + kc * 1024 + lo16);
      A1[kc] = *(const bf16x8*)(F + (size_t)(Ga + 1) * 8192 + kc * 1024 + lo16);
    }
    bf16x8 b0[8], b1[8];
    LOADB(b0, Gb + 0)
    LOADB(b1, Gb + 1)

    f32x16 aA0, aA1, aB0, aB1;
    float rAcc0[16], rAcc1[16];
#pragma unroll
    for (int r = 0; r < 16; ++r) { rAcc0[r] = 0.f; rAcc1[r] = 0.f; }
    float colv = 0.f;

// compute ACc from BB while expiring previous acc AP (exp2 interleaved per kc)
#define PROC(AC0, AC1, BB, AP0, AP1)                                           \
    AC0 = MFMA32(A0[0], BB[0], Z); AC1 = MFMA32(A1[0], BB[0], Z);              \
    _Pragma("unroll")                                                          \
    for (int kc = 1; kc < 8; ++kc) {                                           \
      AC0 = MFMA32(A0[kc], BB[kc], AC0);                                       \
      AC1 = MFMA32(A1[kc], BB[kc], AC1);                                       \
      const int r0 = 2 * (kc - 1), r1 = r0 + 1;                                \
      float e0 = __builtin_amdgcn_exp2f(AP0[r0]);                              \
      float e1 = __builtin_amdgcn_exp2f(AP0[r1]);                              \
      float e2 = __builtin_amdgcn_exp2f(AP1[r0]);                              \
      float e3 = __builtin_amdgcn_exp2f(AP1[r1]);                              \
      rAcc0[r0] += e0; rAcc0[r1] += e1; rAcc1[r0] += e2; rAcc1[r1] += e3;      \
      colv += (e0 + e1) + (e2 + e3);                                           \
    }                                                                          \
    { float e0 = __builtin_amdgcn_exp2f(AP0[14]);                              \
      float e1 = __builtin_amdgcn_exp2f(AP0[15]);                              \
      float e2 = __builtin_amdgcn_exp2f(AP1[14]);                              \
      float e3 = __builtin_amdgcn_exp2f(AP1[15]);                              \
      rAcc0[14] += e0; rAcc0[15] += e1; rAcc1[14] += e2; rAcc1[15] += e3;      \
      colv += (e0 + e1) + (e2 + e3); }

#define FINCOL(CT) {                                                           \
    float cv = colv + __shfl_xor(colv, 32, 64);                                \
    if (!diag && lane < 32) colLds[wave * 128 + (CT) * 32 + lane] = cv;        \
    colv = 0.f; }

    // tile 0: MFMA only
    aA0 = MFMA32(A0[0], b0[0], Z); aA1 = MFMA32(A1[0], b0[0], Z);
#pragma unroll
    for (int kc = 1; kc < 8; ++kc) {
      aA0 = MFMA32(A0[kc], b0[kc], aA0);
      aA1 = MFMA32(A1[kc], b0[kc], aA1);
    }
    LOADB(b0, Gb + 2)
    PROC(aB0, aB1, b1, aA0, aA1)      // tile1, expires tile0
    FINCOL(0)
    LOADB(b1, Gb + 3)
    PROC(aA0, aA1, b0, aB0, aB1)      // tile2, expires tile1
    FINCOL(1)
    PROC(aB0, aB1, b1, aA0, aA1)      // tile3, expires tile2
    FINCOL(2)
#pragma unroll
    for (int r = 0; r < 16; ++r) {    // expire tile3
      float e0 = __builtin_amdgcn_exp2f(aB0[r]);
      float e1 = __builtin_amdgcn_exp2f(aB1[r]);
      rAcc0[r] += e0; rAcc1[r] += e1;
      colv += e0 + e1;
    }
    FINCOL(3)

    __syncthreads();
    if (!diag) {
      const float v = colLds[tid] + colLds[128 + tid];
      part[(size_t)I * MM + J * 128 + tid] = v;
    }

    // row-sum reduce across the 32 col-lanes (within each half)
#pragma unroll
    for (int m = 1; m < 32; m <<= 1)
#pragma unroll
      for (int r = 0; r < 16; ++r) {
        rAcc0[r] += __shfl_xor(rAcc0[r], m, 32);
        rAcc1[r] += __shfl_xor(rAcc1[r], m, 32);
      }
    if ((lane & 31) == 0) {
      const int rbase = I * 128 + wave * 64;
#pragma unroll
      for (int r = 0; r < 16; ++r) {
        const int rl = (r & 3) + 8 * (r >> 2) + 4 * lh2;
        part[(size_t)J * MM + rbase + rl] = rAcc0[r];
        part[(size_t)J * MM + rbase + 32 + rl] = rAcc1[r];
      }
    }
#undef PROC
#undef FINCOL
  } else {
    // ================= own/pos path =================
    const int bid2 = blockIdx.x - NSYM;
    const int c = bid2 >> 1, q = bid2 & 1;
    const int Ga = c * 8 + q * 4 + wave * 2;
    const int c8 = c * 8;

    bf16x8 A0[8], A1[8];
#pragma unroll
    for (int kc = 0; kc < 8; ++kc) {
      A0[kc] = *(const bf16x8*)(F + (size_t)Ga * 8192 + kc * 1024 + lo16);
      A1[kc] = *(const bf16x8*)(F + (size_t)(Ga + 1) * 8192 + kc * 1024 + lo16);
    }
    bf16x8 b0[8], b1[8];
    float rAcc0[16], rAcc1[16];
#pragma unroll
    for (int r = 0; r < 16; ++r) { rAcc0[r] = 0.f; rAcc1[r] = 0.f; }

#define OWNTILE(BB) {                                                          \
    f32x16 a0 = MFMA32(A0[0], BB[0], Z), a1 = MFMA32(A1[0], BB[0], Z);         \
    _Pragma("unroll")                                                          \
    for (int kc = 1; kc < 8; ++kc) {                                           \
      a0 = MFMA32(A0[kc], BB[kc], a0); a1 = MFMA32(A1[kc], BB[kc], a1); }      \
    _Pragma("unroll")                                                          \
    for (int r = 0; r < 16; ++r) {                                             \
      rAcc0[r] += __builtin_amdgcn_exp2f(a0[r]);                               \
      rAcc1[r] += __builtin_amdgcn_exp2f(a1[r]); } }

#define REDUCEW(DST) {                                                         \
    float t0[16], t1[16];                                                      \
    _Pragma("unroll")                                                          \
    for (int r = 0; r < 16; ++r) { t0[r] = rAcc0[r]; t1[r] = rAcc1[r]; }       \
    _Pragma("unroll")                                                          \
    for (int m = 1; m < 32; m <<= 1)                                           \
      _Pragma("unroll")                                                        \
      for (int r = 0; r < 16; ++r) {                                           \
        t0[r] += __shfl_xor(t0[r], m, 32);                                     \
        t1[r] += __shfl_xor(t1[r], m, 32); }                                   \
    if ((lane & 31) == 0) {                                                    \
      const int rbase = c * 256 + q * 128 + wave * 64;                         \
      _Pragma("unroll")                                                        \
      for (int r = 0; r < 16; ++r) {                                           \
        const int rl = (r & 3) + 8 * (r >> 2) + 4 * lh2;                       \
        DST[rbase + rl] = t0[r];                                               \
        DST[rbase + 32 + rl] = t1[r]; } } }

    LOADB(b0, c8 + 0)
    LOADB(b1, c8 + 1)  OWNTILE(b0)
    LOADB(b0, c8 + 2)  OWNTILE(b1)
    LOADB(b1, c8 + 3)  OWNTILE(b0)
    LOADB(b0, c8 + 4)  OWNTILE(b1)
    REDUCEW(posArr)                      // tiles 0..3 = first 128 cols
    LOADB(b1, c8 + 5)  OWNTILE(b0)
    LOADB(b0, c8 + 6)  OWNTILE(b1)
    LOADB(b1, c8 + 7)  OWNTILE(b0)
    OWNTILE(b1)
    REDUCEW(ownArr)                      // all 8 tiles = full own block
#undef OWNTILE
#undef REDUCEW
  }
#undef LOADB
}

// ---------------------------------------------------------------------------
// Kernel 4: per-row loss + in-block reduction -> 50 partial sums
// ---------------------------------------------------------------------------
__global__ void finalize_rows(const float* __restrict__ part,
                              const float* __restrict__ ownArr,
                              const float* __restrict__ posArr,
                              float* __restrict__ partial) {
  __shared__ float red[4];
  const int t = threadIdx.x;
  const int p = blockIdx.x * 256 + t;
  float a = 0.f;
#pragma unroll
  for (int b = 0; b < NBLK; ++b) a += part[(size_t)b * MM + p];
  float rl = logf(a - ownArr[p]) - logf(posArr[p]);
#pragma unroll
  for (int m = 1; m < 64; m <<= 1) rl += __shfl_xor(rl, m, 64);
  if ((t & 63) == 0) red[t >> 6] = rl;
  __syncthreads();
  if (t == 0) partial[blockIdx.x] = red[0] + red[1] + red[2] + red[3];
}

// ---------------------------------------------------------------------------
// Kernel 5: mean -> scalar (one wave over 50 partials)
// ---------------------------------------------------------------------------
__global__ void final_reduce(const float* __restrict__ partial, float* __restrict__ out) {
  const int t = threadIdx.x;   // 64 threads
  float s = (t < MM / 256) ? partial[t] : 0.f;
#pragma unroll
  for (int m = 1; m < 64; m <<= 1) s += __shfl_xor(s, m, 64);
  if (t == 0) out[0] = s * (1.0f / MM);
}

extern "C" void kernel_launch(void* const* d_in, const int* in_sizes, int n_in,
                              void* d_out, int out_size, void* d_ws, size_t ws_size,
                              hipStream_t stream) {
  const float* prob = (const float*)d_in[0];
  const float* zi   = (const float*)d_in[1];
  const float* zj   = (const float*)d_in[2];
  float* out = (float*)d_out;

  char* ws = (char*)d_ws;
  char*  FT       = ws;                                  // 3,276,800 B
  float* part     = (float*)(ws + 3276800);              // 100*12800*4 = 5,120,000 B
  float* ownArr   = (float*)(ws + 8396800);              //    51,200 B
  float* posArr   = (float*)(ws + 8448000);              //    51,200 B
  float* partial  = (float*)(ws + 8499200);              //       256 B
  int*   topk     = (int*)  (ws + 8499456);              //    25,600 B
  int*   candCnt  = (int*)  (ws + 8525056);              //       256 B
  int*   candIdx  = (int*)  (ws + 8525312);              //   409,600 B
  float* candVal  = (float*)(ws + 8934912);              //   409,600 B

  hipMemsetAsync(candCnt, 0, 256, stream);
  cand_kernel   <<<(BB * CC + 255) / 256, 256, 0, stream>>>(prob, candCnt, candIdx, candVal);
  select_kernel <<<CC, 256, 0, stream>>>(prob, candCnt, candIdx, candVal, topk);
  gather_norm   <<<MM / 4, 256, 0, stream>>>(zi, zj, topk, FT);
  sim_sym_kernel<<<NSYM + 2 * CC, 128, 0, stream>>>(FT, part, ownArr, posArr);
  finalize_rows <<<MM / 256, 256, 0, stream>>>(part, ownArr, posArr, partial);
  final_reduce  <<<1, 64, 0, stream>>>(partial, out);
}

// Round 9
// 137.115 us; speedup vs baseline: 1.8771x; 1.5609x over previous
//
#include <hip/hip_runtime.h>
#include <math.h>

#define BB 16384      // B
#define CC 50         // clusters
#define KK 128        // top-K
#define DD 128        // feature dim
#define MM 12800      // CC*2*KK rows of F
#define NBLK 100      // 128-row blocks of F
#define NSYM 5050     // upper-triangular 128x128 tile pairs (incl. 100 diagonal)
#define MAXCAND 2048
#define TCAND 0.97f
#define NPART 64      // candidate partitions (256 rows each)
#define RPP 256       // rows per partition
#define PCAP 32       // per (partition,cluster) capacity; expected ~7.7
// F rows are pre-scaled by SQS = sqrt(2/ln2): dot(F,F) = sim * 2/ln2, so
// exp(sim/TEMP) = exp2(dot) directly. Single bf16 product (validated r8:
// absmax 0.0 vs reference).
#define SQS 1.6986436f

// Tiled F layout: for each 32-row group G (400 groups), each kc (16-K chunk,
// 8 chunks), 64 granules of 16B lane-ordered for mfma_32x32x16_bf16 operands.
// One fragment load = contiguous 1KB wave load at G*8192 + kc*1024 + lane*16.

typedef __bf16 bf16x8 __attribute__((ext_vector_type(8)));
typedef float f32x16 __attribute__((ext_vector_type(16)));

#define MFMA32(a, b, c) __builtin_amdgcn_mfma_f32_32x32x16_bf16(a, b, c, 0, 0, 0)

__device__ inline unsigned short f2bf(float x) {
  unsigned u = __float_as_uint(x);
  unsigned r = (u + 0x7fffu + ((u >> 16) & 1u)) >> 16;
  return (unsigned short)r;
}

// ---------------------------------------------------------------------------
// Kernel 1a: candidate collection, ZERO global atomics. Block b owns rows
// [b*256, b*256+256) x all 50 clusters (51KB coalesced read, L2-resident).
// Slot allocation via LDS atomics; per-(partition,cluster) capacity PCAP with
// exact fallback if exceeded (counts stored uncapped for detection).
// ---------------------------------------------------------------------------
__global__ void cand_kernel(const float* __restrict__ prob, int* __restrict__ candCnt,
                            int* __restrict__ candIdx, float* __restrict__ candVal) {
  __shared__ int lcnt[CC];
  const int b = blockIdx.x, t = threadIdx.x;
  if (t < CC) lcnt[t] = 0;
  __syncthreads();
  const int base = b * RPP * CC;
  for (int i = t; i < RPP * CC; i += 256) {
    const float v = prob[base + i];
    if (v >= TCAND) {
      const int r = i / CC, c = i - r * CC;
      const int slot = atomicAdd(&lcnt[c], 1);
      if (slot < PCAP) {
        candIdx[(b * CC + c) * PCAP + slot] = b * RPP + r;
        candVal[(b * CC + c) * PCAP + slot] = v;
      }
    }
  }
  __syncthreads();
  if (t < CC) candCnt[b * CC + t] = lcnt[t];
}

// ---------------------------------------------------------------------------
// Kernel 1b: per-cluster exact top-K. Fast path: shuffle-scan the 64
// partition counts, parallel-gather candidates into LDS, radix select.
// Slow path (overflow / undercount): full-column radix select (exact).
// ---------------------------------------------------------------------------
__global__ void select_kernel(const float* __restrict__ prob,
                              const int* __restrict__ candCnt,
                              const int* __restrict__ candIdx,
                              const float* __restrict__ candVal,
                              int* __restrict__ topk) {
  __shared__ float vals[MAXCAND];
  __shared__ int   idxs[MAXCAND];
  __shared__ int hist[256];
  __shared__ int sChosen, sKrem, gtc, eqc, bad;
  __shared__ int pref[NPART + 1];
  __shared__ int eqIdx[256];
  const int c = blockIdx.x, t = threadIdx.x;

  if (t == 0) bad = 0;
  __syncthreads();
  int cnt_p = 0;
  if (t < NPART) {
    cnt_p = candCnt[t * CC + c];
    if (cnt_p > PCAP) bad = 1;
    int x = cnt_p;
#pragma unroll
    for (int d = 1; d < 64; d <<= 1) {
      int y = __shfl_up(x, d, 64);
      if (t >= d) x += y;
    }
    pref[t + 1] = x;
    if (t == 0) pref[0] = 0;
  }
  __syncthreads();
  const int total = pref[NPART];

  if (!bad && total >= KK && total <= MAXCAND) {
    // ---- fast path ----
    if (t < NPART) {
      const int o = pref[t];
      for (int j = 0; j < cnt_p; ++j) {
        vals[o + j] = candVal[(t * CC + c) * PCAP + j];
        idxs[o + j] = candIdx[(t * CC + c) * PCAP + j];
      }
    }
    __syncthreads();
    unsigned prefix = 0;
    int krem = KK;
    for (int pass = 0; pass < 4; ++pass) {
      const int shift = 24 - pass * 8;
      hist[t] = 0;
      __syncthreads();
      for (int j = t; j < total; j += 256) {
        unsigned u = __float_as_uint(vals[j]);
        bool match = (pass == 0) || ((u >> (shift + 8)) == (prefix >> (shift + 8)));
        if (match) atomicAdd(&hist[(u >> shift) & 255], 1);
      }
      __syncthreads();
      if (t == 0) {
        int kr = krem, b2 = 255;
        for (; b2 > 0; --b2) {
          if (kr > hist[b2]) kr -= hist[b2];
          else break;
        }
        sChosen = b2; sKrem = kr;
      }
      __syncthreads();
      prefix |= ((unsigned)sChosen) << shift;
      krem = sKrem;
      __syncthreads();
    }
    const unsigned T = prefix;
    if (t == 0) { gtc = 0; eqc = 0; }
    __syncthreads();
    for (int j = t; j < total; j += 256) {
      unsigned u = __float_as_uint(vals[j]);
      if (u > T) {
        int pos = atomicAdd(&gtc, 1);
        topk[c * KK + pos] = idxs[j];
      } else if (u == T) {
        int e = atomicAdd(&eqc, 1);
        if (e < 256) eqIdx[e] = idxs[j];
      }
    }
    __syncthreads();
    if (t == 0) {
      int base = gtc;
      int ec = eqc < 256 ? eqc : 256;
      for (int j2 = 0; j2 < krem; ++j2) {
        int bi = -1, bv = 0x7fffffff;
        for (int q = 0; q < ec; ++q) {
          int v = eqIdx[q];
          if (v >= 0 && v < bv) { bv = v; bi = q; }
        }
        topk[c * KK + base + j2] = bv;
        eqIdx[bi] = -1;
      }
    }
  } else {
    // ---- exact fallback: full strided column radix select ----
    unsigned prefix = 0;
    int krem = KK;
    for (int pass = 0; pass < 4; ++pass) {
      const int shift = 24 - pass * 8;
      hist[t] = 0;
      __syncthreads();
      for (int i = t; i < BB; i += 256) {
        unsigned u = __float_as_uint(prob[i * CC + c]);
        bool match = (pass == 0) || ((u >> (shift + 8)) == (prefix >> (shift + 8)));
        if (match) atomicAdd(&hist[(u >> shift) & 255], 1);
      }
      __syncthreads();
      if (t == 0) {
        int kr = krem, b2 = 255;
        for (; b2 > 0; --b2) {
          if (kr > hist[b2]) kr -= hist[b2];
          else break;
        }
        sChosen = b2; sKrem = kr;
      }
      __syncthreads();
      prefix |= ((unsigned)sChosen) << shift;
      krem = sKrem;
      __syncthreads();
    }
    const unsigned T = prefix;
    if (t == 0) { gtc = 0; eqc = 0; }
    __syncthreads();
    for (int i = t; i < BB; i += 256) {
      unsigned u = __float_as_uint(prob[i * CC + c]);
      if (u > T) {
        int pos = atomicAdd(&gtc, 1);
        topk[c * KK + pos] = i;
      } else if (u == T) {
        int e = atomicAdd(&eqc, 1);
        if (e < 256) eqIdx[e] = i;
      }
    }
    __syncthreads();
    if (t == 0) {
      int base = gtc;
      int ec = eqc < 256 ? eqc : 256;
      for (int j = 0; j < krem; ++j) {
        int bi = -1, bv = 0x7fffffff;
        for (int q = 0; q < ec; ++q) {
          int v = eqIdx[q];
          if (v >= 0 && v < bv) { bv = v; bi = q; }
        }
        topk[c * KK + base + j] = bv;
        eqIdx[bi] = -1;
      }
    }
  }
}

// ---------------------------------------------------------------------------
// Kernel 2: gather + L2-normalize + SQS scale + bf16, tiled layout.
// ---------------------------------------------------------------------------
__global__ void gather_norm(const float* __restrict__ zi, const float* __restrict__ zj,
                            const int* __restrict__ topk, char* __restrict__ FT) {
  const int gw = (blockIdx.x * 256 + threadIdx.x) >> 6;
  const int lane = threadIdx.x & 63;
  if (gw >= MM) return;
  const int c = gw >> 8, p = gw & 255;
  const int idx = topk[c * KK + (p & (KK - 1))];
  const float* src = (p < KK ? zi : zj) + (size_t)idx * DD;
  float2 v = ((const float2*)src)[lane];
  float ss = fmaf(v.x, v.x, v.y * v.y);
#pragma unroll
  for (int m = 1; m < 64; m <<= 1) ss += __shfl_xor(ss, m, 64);
  const float scale = SQS / fmaxf(sqrtf(ss), 1e-8f);
  unsigned short ah = f2bf(v.x * scale), bh = f2bf(v.y * scale);
  unsigned hp = ((unsigned)bh << 16) | ah;
  const int k2 = 2 * lane;
  const int kc = k2 >> 4;          // 16-K chunk
  const int kk = k2 & 15;
  const size_t off = (size_t)(gw >> 5) * 8192 + (size_t)kc * 1024 +
                     (size_t)(((kk >> 3) * 32 + (gw & 31)) * 16 + (kk & 7) * 2);
  *(unsigned*)(FT + off) = hp;
}

// ---------------------------------------------------------------------------
// Kernel 3: symmetric fused sim (unchanged from round 8; absmax 0.0).
// ---------------------------------------------------------------------------
__global__ __launch_bounds__(128, 2) void sim_sym_kernel(
    const char* __restrict__ F, float* __restrict__ part,
    float* __restrict__ ownArr, float* __restrict__ posArr) {
  __shared__ float colLds[256];
  const int tid = threadIdx.x;
  const int lane = tid & 63, wave = tid >> 6;
  const int lh2 = lane >> 5;
  const size_t lo16 = (size_t)lane * 16;

  f32x16 Z = {};

#define LOADB(BUF, GIDX) {                                                     \
    _Pragma("unroll")                                                          \
    for (int kc = 0; kc < 8; ++kc)                                             \
      BUF[kc] = *(const bf16x8*)(F + (size_t)(GIDX) * 8192 + kc * 1024 + lo16);\
  }

  if (blockIdx.x < NSYM) {
    const int k = blockIdx.x;
    int I = (int)((201.0f - sqrtf(40401.0f - 8.0f * (float)k)) * 0.5f);
    while ((I + 1) * NBLK - ((I + 1) * I) / 2 <= k) ++I;
    while (I * NBLK - (I * (I - 1)) / 2 > k) --I;
    const int J = I + (k - (I * NBLK - (I * (I - 1)) / 2));
    const bool diag = (I == J);
    const int Ga = I * 4 + wave * 2;
    const int Gb = J * 4;

    bf16x8 A0[8], A1[8];
#pragma unroll
    for (int kc = 0; kc < 8; ++kc) {
      A0[kc] = *(const bf16x8*)(F + (size_t)Ga * 8192 + kc * 1024 + lo16);
      A1[kc] = *(const bf16x8*)(F + (size_t)(Ga + 1) * 8192 + kc * 1024 + lo16);
    }
    bf16x8 b0[8], b1[8];
    LOADB(b0, Gb + 0)
    LOADB(b1, Gb + 1)

    f32x16 aA0, aA1, aB0, aB1;
    float rAcc0[16], rAcc1[16];
#pragma unroll
    for (int r = 0; r < 16; ++r) { rAcc0[r] = 0.f; rAcc1[r] = 0.f; }
    float colv = 0.f;

#define PROC(AC0, AC1, BB_, AP0, AP1)                                          \
    AC0 = MFMA32(A0[0], BB_[0], Z); AC1 = MFMA32(A1[0], BB_[0], Z);            \
    _Pragma("unroll")                                                          \
    for (int kc = 1; kc < 8; ++kc) {                                           \
      AC0 = MFMA32(A0[kc], BB_[kc], AC0);                                      \
      AC1 = MFMA32(A1[kc], BB_[kc], AC1);                                      \
      const int r0 = 2 * (kc - 1), r1 = r0 + 1;                                \
      float e0 = __builtin_amdgcn_exp2f(AP0[r0]);                              \
      float e1 = __builtin_amdgcn_exp2f(AP0[r1]);                              \
      float e2 = __builtin_amdgcn_exp2f(AP1[r0]);                              \
      float e3 = __builtin_amdgcn_exp2f(AP1[r1]);                              \
      rAcc0[r0] += e0; rAcc0[r1] += e1; rAcc1[r0] += e2; rAcc1[r1] += e3;      \
      colv += (e0 + e1) + (e2 + e3);                                           \
    }                                                                          \
    { float e0 = __builtin_amdgcn_exp2f(AP0[14]);                              \
      float e1 = __builtin_amdgcn_exp2f(AP0[15]);                              \
      float e2 = __builtin_amdgcn_exp2f(AP1[14]);                              \
      float e3 = __builtin_amdgcn_exp2f(AP1[15]);                              \
      rAcc0[14] += e0; rAcc0[15] += e1; rAcc1[14] += e2; rAcc1[15] += e3;      \
      colv += (e0 + e1) + (e2 + e3); }

#define FINCOL(CT) {                                                           \
    float cv = colv + __shfl_xor(colv, 32, 64);                                \
    if (!diag && lane < 32) colLds[wave * 128 + (CT) * 32 + lane] = cv;        \
    colv = 0.f; }

    aA0 = MFMA32(A0[0], b0[0], Z); aA1 = MFMA32(A1[0], b0[0], Z);
#pragma unroll
    for (int kc = 1; kc < 8; ++kc) {
      aA0 = MFMA32(A0[kc], b0[kc], aA0);
      aA1 = MFMA32(A1[kc], b0[kc], aA1);
    }
    LOADB(b0, Gb + 2)
    PROC(aB0, aB1, b1, aA0, aA1)
    FINCOL(0)
    LOADB(b1, Gb + 3)
    PROC(aA0, aA1, b0, aB0, aB1)
    FINCOL(1)
    PROC(aB0, aB1, b1, aA0, aA1)
    FINCOL(2)
#pragma unroll
    for (int r = 0; r < 16; ++r) {
      float e0 = __builtin_amdgcn_exp2f(aB0[r]);
      float e1 = __builtin_amdgcn_exp2f(aB1[r]);
      rAcc0[r] += e0; rAcc1[r] += e1;
      colv += e0 + e1;
    }
    FINCOL(3)

    __syncthreads();
    if (!diag) {
      const float v = colLds[tid] + colLds[128 + tid];
      part[(size_t)I * MM + J * 128 + tid] = v;
    }

#pragma unroll
    for (int m = 1; m < 32; m <<= 1)
#pragma unroll
      for (int r = 0; r < 16; ++r) {
        rAcc0[r] += __shfl_xor(rAcc0[r], m, 32);
        rAcc1[r] += __shfl_xor(rAcc1[r], m, 32);
      }
    if ((lane & 31) == 0) {
      const int rbase = I * 128 + wave * 64;
#pragma unroll
      for (int r = 0; r < 16; ++r) {
        const int rl = (r & 3) + 8 * (r >> 2) + 4 * lh2;
        part[(size_t)J * MM + rbase + rl] = rAcc0[r];
        part[(size_t)J * MM + rbase + 32 + rl] = rAcc1[r];
      }
    }
#undef PROC
#undef FINCOL
  } else {
    const int bid2 = blockIdx.x - NSYM;
    const int c = bid2 >> 1, q = bid2 & 1;
    const int Ga = c * 8 + q * 4 + wave * 2;
    const int c8 = c * 8;

    bf16x8 A0[8], A1[8];
#pragma unroll
    for (int kc = 0; kc < 8; ++kc) {
      A0[kc] = *(const bf16x8*)(F + (size_t)Ga * 8192 + kc * 1024 + lo16);
      A1[kc] = *(const bf16x8*)(F + (size_t)(Ga + 1) * 8192 + kc * 1024 + lo16);
    }
    bf16x8 b0[8], b1[8];
    float rAcc0[16], rAcc1[16];
#pragma unroll
    for (int r = 0; r < 16; ++r) { rAcc0[r] = 0.f; rAcc1[r] = 0.f; }

#define OWNTILE(BB_) {                                                         \
    f32x16 a0 = MFMA32(A0[0], BB_[0], Z), a1 = MFMA32(A1[0], BB_[0], Z);       \
    _Pragma("unroll")                                                          \
    for (int kc = 1; kc < 8; ++kc) {                                           \
      a0 = MFMA32(A0[kc], BB_[kc], a0); a1 = MFMA32(A1[kc], BB_[kc], a1); }    \
    _Pragma("unroll")                                                          \
    for (int r = 0; r < 16; ++r) {                                             \
      rAcc0[r] += __builtin_amdgcn_exp2f(a0[r]);                               \
      rAcc1[r] += __builtin_amdgcn_exp2f(a1[r]); } }

#define REDUCEW(DST) {                                                         \
    float t0[16], t1[16];                                                      \
    _Pragma("unroll")                                                          \
    for (int r = 0; r < 16; ++r) { t0[r] = rAcc0[r]; t1[r] = rAcc1[r]; }       \
    _Pragma("unroll")                                                          \
    for (int m = 1; m < 32; m <<= 1)                                           \
      _Pragma("unroll")                                                        \
      for (int r = 0; r < 16; ++r) {                                           \
        t0[r] += __shfl_xor(t0[r], m, 32);                                     \
        t1[r] += __shfl_xor(t1[r], m, 32); }                                   \
    if ((lane & 31) == 0) {                                                    \
      const int rbase = c * 256 + q * 128 + wave * 64;                         \
      _Pragma("unroll")                                                        \
      for (int r = 0; r < 16; ++r) {                                           \
        const int rl = (r & 3) + 8 * (r >> 2) + 4 * lh2;                       \
        DST[rbase + rl] = t0[r];                                               \
        DST[rbase + 32 + rl] = t1[r]; } } }

    LOADB(b0, c8 + 0)
    LOADB(b1, c8 + 1)  OWNTILE(b0)
    LOADB(b0, c8 + 2)  OWNTILE(b1)
    LOADB(b1, c8 + 3)  OWNTILE(b0)
    LOADB(b0, c8 + 4)  OWNTILE(b1)
    REDUCEW(posArr)
    LOADB(b1, c8 + 5)  OWNTILE(b0)
    LOADB(b0, c8 + 6)  OWNTILE(b1)
    LOADB(b1, c8 + 7)  OWNTILE(b0)
    OWNTILE(b1)
    REDUCEW(ownArr)
#undef OWNTILE
#undef REDUCEW
  }
#undef LOADB
}

// ---------------------------------------------------------------------------
// Kernel 4: per-row loss + in-block reduction -> 50 partial sums
// ---------------------------------------------------------------------------
__global__ void finalize_rows(const float* __restrict__ part,
                              const float* __restrict__ ownArr,
                              const float* __restrict__ posArr,
                              float* __restrict__ partial) {
  __shared__ float red[4];
  const int t = threadIdx.x;
  const int p = blockIdx.x * 256 + t;
  float a = 0.f;
#pragma unroll
  for (int b = 0; b < NBLK; ++b) a += part[(size_t)b * MM + p];
  float rl = logf(a - ownArr[p]) - logf(posArr[p]);
#pragma unroll
  for (int m = 1; m < 64; m <<= 1) rl += __shfl_xor(rl, m, 64);
  if ((t & 63) == 0) red[t >> 6] = rl;
  __syncthreads();
  if (t == 0) partial[blockIdx.x] = red[0] + red[1] + red[2] + red[3];
}

// ---------------------------------------------------------------------------
// Kernel 5: mean -> scalar (one wave over 50 partials)
// ---------------------------------------------------------------------------
__global__ void final_reduce(const float* __restrict__ partial, float* __restrict__ out) {
  const int t = threadIdx.x;   // 64 threads
  float s = (t < MM / 256) ? partial[t] : 0.f;
#pragma unroll
  for (int m = 1; m < 64; m <<= 1) s += __shfl_xor(s, m, 64);
  if (t == 0) out[0] = s * (1.0f / MM);
}

extern "C" void kernel_launch(void* const* d_in, const int* in_sizes, int n_in,
                              void* d_out, int out_size, void* d_ws, size_t ws_size,
                              hipStream_t stream) {
  const float* prob = (const float*)d_in[0];
  const float* zi   = (const float*)d_in[1];
  const float* zj   = (const float*)d_in[2];
  float* out = (float*)d_out;

  char* ws = (char*)d_ws;
  char*  FT       = ws;                                  // 3,276,800 B
  float* part     = (float*)(ws + 3276800);              // 5,120,000 B
  float* ownArr   = (float*)(ws + 8396800);              //    51,200 B
  float* posArr   = (float*)(ws + 8448000);              //    51,200 B
  float* partial  = (float*)(ws + 8499200);              //       256 B
  int*   topk     = (int*)  (ws + 8499456);              //    25,600 B
  int*   candCnt  = (int*)  (ws + 8525056);              // 64*50*4 = 12,800 B
  int*   candIdx  = (int*)  (ws + 8537856);              // 64*50*32*4 = 409,600 B
  float* candVal  = (float*)(ws + 8947456);              //   409,600 B

  cand_kernel   <<<NPART, 256, 0, stream>>>(prob, candCnt, candIdx, candVal);
  select_kernel <<<CC, 256, 0, stream>>>(prob, candCnt, candIdx, candVal, topk);
  gather_norm   <<<MM / 4, 256, 0, stream>>>(zi, zj, topk, FT);
  sim_sym_kernel<<<NSYM + 2 * CC, 128, 0, stream>>>(FT, part, ownArr, posArr);
  finalize_rows <<<MM / 256, 256, 0, stream>>>(part, ownArr, posArr, partial);
  final_reduce  <<<1, 64, 0, stream>>>(partial, out);
}

// Round 10
// 130.923 us; speedup vs baseline: 1.9659x; 1.0473x over previous
//
#include <hip/hip_runtime.h>
#include <math.h>

#define BB 16384      // B
#define CC 50         // clusters
#define KK 128        // top-K
#define DD 128        // feature dim
#define MM 12800      // CC*2*KK rows of F
#define NBLK 100      // 128-row blocks of F
#define NCHUNK 13     // J-chunks per row (chunk = 8 tiles)
#define CHT 8         // tiles per chunk
#define MAXCAND 2048
#define TCAND 0.97f
#define NPART 64      // candidate partitions (256 rows each)
#define RPP 256       // rows per partition
#define PCAP 32       // per (partition,cluster) capacity; expected ~7.7
// F rows pre-scaled by SQS = sqrt(2/ln2): dot(F,F) = sim*2/ln2 -> exp2 direct.
// Single bf16 product (validated r8/r9: absmax 0.0 vs reference).
#define SQS 1.6986436f

// Tiled F layout: for each 32-row group G (400 groups), each kc (16-K chunk,
// 8 chunks), 64 granules of 16B lane-ordered for mfma_32x32x16_bf16 operands.
// One fragment load = contiguous 1KB wave load at G*8192 + kc*1024 + lane*16.

typedef __bf16 bf16x8 __attribute__((ext_vector_type(8)));
typedef float f32x16 __attribute__((ext_vector_type(16)));

#define MFMA32(a, b, c) __builtin_amdgcn_mfma_f32_32x32x16_bf16(a, b, c, 0, 0, 0)

__device__ inline unsigned short f2bf(float x) {
  unsigned u = __float_as_uint(x);
  unsigned r = (u + 0x7fffu + ((u >> 16) & 1u)) >> 16;
  return (unsigned short)r;
}

// ---------------------------------------------------------------------------
// Kernel 1a: candidate collection, zero global atomics (r9, validated).
// ---------------------------------------------------------------------------
__global__ void cand_kernel(const float* __restrict__ prob, int* __restrict__ candCnt,
                            int* __restrict__ candIdx, float* __restrict__ candVal) {
  __shared__ int lcnt[CC];
  const int b = blockIdx.x, t = threadIdx.x;
  if (t < CC) lcnt[t] = 0;
  __syncthreads();
  const int base = b * RPP * CC;
  for (int i = t; i < RPP * CC; i += 256) {
    const float v = prob[base + i];
    if (v >= TCAND) {
      const int r = i / CC, c = i - r * CC;
      const int slot = atomicAdd(&lcnt[c], 1);
      if (slot < PCAP) {
        candIdx[(b * CC + c) * PCAP + slot] = b * RPP + r;
        candVal[(b * CC + c) * PCAP + slot] = v;
      }
    }
  }
  __syncthreads();
  if (t < CC) candCnt[b * CC + t] = lcnt[t];
}

// ---------------------------------------------------------------------------
// Kernel 1b: per-cluster exact top-K (r9, validated).
// ---------------------------------------------------------------------------
__global__ void select_kernel(const float* __restrict__ prob,
                              const int* __restrict__ candCnt,
                              const int* __restrict__ candIdx,
                              const float* __restrict__ candVal,
                              int* __restrict__ topk) {
  __shared__ float vals[MAXCAND];
  __shared__ int   idxs[MAXCAND];
  __shared__ int hist[256];
  __shared__ int sChosen, sKrem, gtc, eqc, bad;
  __shared__ int pref[NPART + 1];
  __shared__ int eqIdx[256];
  const int c = blockIdx.x, t = threadIdx.x;

  if (t == 0) bad = 0;
  __syncthreads();
  int cnt_p = 0;
  if (t < NPART) {
    cnt_p = candCnt[t * CC + c];
    if (cnt_p > PCAP) bad = 1;
    int x = cnt_p;
#pragma unroll
    for (int d = 1; d < 64; d <<= 1) {
      int y = __shfl_up(x, d, 64);
      if (t >= d) x += y;
    }
    pref[t + 1] = x;
    if (t == 0) pref[0] = 0;
  }
  __syncthreads();
  const int total = pref[NPART];

  if (!bad && total >= KK && total <= MAXCAND) {
    if (t < NPART) {
      const int o = pref[t];
      for (int j = 0; j < cnt_p; ++j) {
        vals[o + j] = candVal[(t * CC + c) * PCAP + j];
        idxs[o + j] = candIdx[(t * CC + c) * PCAP + j];
      }
    }
    __syncthreads();
    unsigned prefix = 0;
    int krem = KK;
    for (int pass = 0; pass < 4; ++pass) {
      const int shift = 24 - pass * 8;
      hist[t] = 0;
      __syncthreads();
      for (int j = t; j < total; j += 256) {
        unsigned u = __float_as_uint(vals[j]);
        bool match = (pass == 0) || ((u >> (shift + 8)) == (prefix >> (shift + 8)));
        if (match) atomicAdd(&hist[(u >> shift) & 255], 1);
      }
      __syncthreads();
      if (t == 0) {
        int kr = krem, b2 = 255;
        for (; b2 > 0; --b2) {
          if (kr > hist[b2]) kr -= hist[b2];
          else break;
        }
        sChosen = b2; sKrem = kr;
      }
      __syncthreads();
      prefix |= ((unsigned)sChosen) << shift;
      krem = sKrem;
      __syncthreads();
    }
    const unsigned T = prefix;
    if (t == 0) { gtc = 0; eqc = 0; }
    __syncthreads();
    for (int j = t; j < total; j += 256) {
      unsigned u = __float_as_uint(vals[j]);
      if (u > T) {
        int pos = atomicAdd(&gtc, 1);
        topk[c * KK + pos] = idxs[j];
      } else if (u == T) {
        int e = atomicAdd(&eqc, 1);
        if (e < 256) eqIdx[e] = idxs[j];
      }
    }
    __syncthreads();
    if (t == 0) {
      int base = gtc;
      int ec = eqc < 256 ? eqc : 256;
      for (int j2 = 0; j2 < krem; ++j2) {
        int bi = -1, bv = 0x7fffffff;
        for (int q = 0; q < ec; ++q) {
          int v = eqIdx[q];
          if (v >= 0 && v < bv) { bv = v; bi = q; }
        }
        topk[c * KK + base + j2] = bv;
        eqIdx[bi] = -1;
      }
    }
  } else {
    unsigned prefix = 0;
    int krem = KK;
    for (int pass = 0; pass < 4; ++pass) {
      const int shift = 24 - pass * 8;
      hist[t] = 0;
      __syncthreads();
      for (int i = t; i < BB; i += 256) {
        unsigned u = __float_as_uint(prob[i * CC + c]);
        bool match = (pass == 0) || ((u >> (shift + 8)) == (prefix >> (shift + 8)));
        if (match) atomicAdd(&hist[(u >> shift) & 255], 1);
      }
      __syncthreads();
      if (t == 0) {
        int kr = krem, b2 = 255;
        for (; b2 > 0; --b2) {
          if (kr > hist[b2]) kr -= hist[b2];
          else break;
        }
        sChosen = b2; sKrem = kr;
      }
      __syncthreads();
      prefix |= ((unsigned)sChosen) << shift;
      krem = sKrem;
      __syncthreads();
    }
    const unsigned T = prefix;
    if (t == 0) { gtc = 0; eqc = 0; }
    __syncthreads();
    for (int i = t; i < BB; i += 256) {
      unsigned u = __float_as_uint(prob[i * CC + c]);
      if (u > T) {
        int pos = atomicAdd(&gtc, 1);
        topk[c * KK + pos] = i;
      } else if (u == T) {
        int e = atomicAdd(&eqc, 1);
        if (e < 256) eqIdx[e] = i;
      }
    }
    __syncthreads();
    if (t == 0) {
      int base = gtc;
      int ec = eqc < 256 ? eqc : 256;
      for (int j = 0; j < krem; ++j) {
        int bi = -1, bv = 0x7fffffff;
        for (int q = 0; q < ec; ++q) {
          int v = eqIdx[q];
          if (v >= 0 && v < bv) { bv = v; bi = q; }
        }
        topk[c * KK + base + j] = bv;
        eqIdx[bi] = -1;
      }
    }
  }
}

// ---------------------------------------------------------------------------
// Kernel 2: gather + L2-normalize + SQS scale + bf16, tiled layout (r9).
// ---------------------------------------------------------------------------
__global__ void gather_norm(const float* __restrict__ zi, const float* __restrict__ zj,
                            const int* __restrict__ topk, char* __restrict__ FT) {
  const int gw = (blockIdx.x * 256 + threadIdx.x) >> 6;
  const int lane = threadIdx.x & 63;
  if (gw >= MM) return;
  const int c = gw >> 8, p = gw & 255;
  const int idx = topk[c * KK + (p & (KK - 1))];
  const float* src = (p < KK ? zi : zj) + (size_t)idx * DD;
  float2 v = ((const float2*)src)[lane];
  float ss = fmaf(v.x, v.x, v.y * v.y);
#pragma unroll
  for (int m = 1; m < 64; m <<= 1) ss += __shfl_xor(ss, m, 64);
  const float scale = SQS / fmaxf(sqrtf(ss), 1e-8f);
  unsigned short ah = f2bf(v.x * scale), bh = f2bf(v.y * scale);
  unsigned hp = ((unsigned)bh << 16) | ah;
  const int k2 = 2 * lane;
  const int kc = k2 >> 4;
  const int kk = k2 & 15;
  const size_t off = (size_t)(gw >> 5) * 8192 + (size_t)kc * 1024 +
                     (size_t)(((kk >> 3) * 32 + (gw & 31)) * 16 + (kk & 7) * 2);
  *(unsigned*)(FT + off) = hp;
}

// ---------------------------------------------------------------------------
// Kernel 3: PANELIZED symmetric sim. Block (I,q) owns row-block I and up to
// CHT=8 consecutive column tiles J in [I+8q, min(I+8q+8,100)). A fragments
// loaded once per panel; B groups are one contiguous stream of 4*nt groups
// (ping-pong + exp2-interleaved PROC from r8, validated). Row-sums accumulate
// in regs over the whole panel -> slot 100+q. Col-sums batch in 8KB LDS ->
// one barrier + coalesced write; slot I. Diagonal tile: col write skipped.
// Blocks [1300, 1400): own/pos sums (r9 path).
// ---------------------------------------------------------------------------
__global__ __launch_bounds__(128, 2) void sim_sym_kernel(
    const char* __restrict__ F, float* __restrict__ part,
    float* __restrict__ ownArr, float* __restrict__ posArr) {
  __shared__ float colLds[2][1024];
  const int tid = threadIdx.x;
  const int lane = tid & 63, wave = tid >> 6;
  const int lh2 = lane >> 5;
  const size_t lo16 = (size_t)lane * 16;

  f32x16 Z = {};

#define LOADB(BUF, GIDX) {                                                     \
    _Pragma("unroll")                                                          \
    for (int kc = 0; kc < 8; ++kc)                                             \
      BUF[kc] = *(const bf16x8*)(F + (size_t)(GIDX) * 8192 + kc * 1024 + lo16);\
  }

  if (blockIdx.x < NBLK * NCHUNK) {
    const int I = blockIdx.x / NCHUNK, q = blockIdx.x - I * NCHUNK;
    const int J0 = I + q * CHT;
    if (J0 >= NBLK) return;                        // empty chunk
    const int nt = min(CHT, NBLK - J0);
    const int S = nt * 4;                          // column groups in panel
    const int G0 = J0 * 4;
    const int Ga = I * 4 + wave * 2;

    bf16x8 A0[8], A1[8];
#pragma unroll
    for (int kc = 0; kc < 8; ++kc) {
      A0[kc] = *(const bf16x8*)(F + (size_t)Ga * 8192 + kc * 1024 + lo16);
      A1[kc] = *(const bf16x8*)(F + (size_t)(Ga + 1) * 8192 + kc * 1024 + lo16);
    }
    bf16x8 b0[8], b1[8];
    f32x16 aA0, aA1, aB0, aB1;
    float rAcc0[16], rAcc1[16];
#pragma unroll
    for (int r = 0; r < 16; ++r) { rAcc0[r] = 0.f; rAcc1[r] = 0.f; }
    float colv = 0.f;

// compute current colgroup into AC from BB_, expiring previous acc AP
// (exp2 textually interleaved per kc between MFMAs; validated r8)
#define PROC(AC0, AC1, BB_, AP0, AP1)                                          \
    AC0 = MFMA32(A0[0], BB_[0], Z); AC1 = MFMA32(A1[0], BB_[0], Z);            \
    _Pragma("unroll")                                                          \
    for (int kc = 1; kc < 8; ++kc) {                                           \
      AC0 = MFMA32(A0[kc], BB_[kc], AC0);                                      \
      AC1 = MFMA32(A1[kc], BB_[kc], AC1);                                      \
      const int r0 = 2 * (kc - 1), r1 = r0 + 1;                                \
      float e0 = __builtin_amdgcn_exp2f(AP0[r0]);                              \
      float e1 = __builtin_amdgcn_exp2f(AP0[r1]);                              \
      float e2 = __builtin_amdgcn_exp2f(AP1[r0]);                              \
      float e3 = __builtin_amdgcn_exp2f(AP1[r1]);                              \
      rAcc0[r0] += e0; rAcc0[r1] += e1; rAcc1[r0] += e2; rAcc1[r1] += e3;      \
      colv += (e0 + e1) + (e2 + e3);                                           \
    }                                                                          \
    { float e0 = __builtin_amdgcn_exp2f(AP0[14]);                              \
      float e1 = __builtin_amdgcn_exp2f(AP0[15]);                              \
      float e2 = __builtin_amdgcn_exp2f(AP1[14]);                              \
      float e3 = __builtin_amdgcn_exp2f(AP1[15]);                              \
      rAcc0[14] += e0; rAcc0[15] += e1; rAcc1[14] += e2; rAcc1[15] += e3;      \
      colv += (e0 + e1) + (e2 + e3); }

#define FINCOL(S_) {                                                           \
    float cv = colv + __shfl_xor(colv, 32, 64);                                \
    if (lane < 32) colLds[wave][(S_) * 32 + lane] = cv;                        \
    colv = 0.f; }

    // colgroup 0 (nothing to expire yet)
    LOADB(b0, G0)
    aA0 = MFMA32(A0[0], b0[0], Z); aA1 = MFMA32(A1[0], b0[0], Z);
#pragma unroll
    for (int kc = 1; kc < 8; ++kc) {
      aA0 = MFMA32(A0[kc], b0[kc], aA0);
      aA1 = MFMA32(A1[kc], b0[kc], aA1);
    }
    LOADB(b1, G0 + 1)

    int s = 1;
    for (; s + 1 < S; s += 2) {
      PROC(aB0, aB1, b1, aA0, aA1)       // compute cg s, expire cg s-1
      FINCOL(s - 1)
      LOADB(b0, G0 + s + 1)
      PROC(aA0, aA1, b0, aB0, aB1)       // compute cg s+1, expire cg s
      FINCOL(s)
      LOADB(b1, G0 + s + 2)              // s+2 <= S-1 always in range
    }
    // s == S-1: b1 holds cg S-1; aA holds cg S-2 unexpired
    PROC(aB0, aB1, b1, aA0, aA1)
    FINCOL(S - 2)
#pragma unroll
    for (int r = 0; r < 16; ++r) {       // expire cg S-1
      float e0 = __builtin_amdgcn_exp2f(aB0[r]);
      float e1 = __builtin_amdgcn_exp2f(aB1[r]);
      rAcc0[r] += e0; rAcc1[r] += e1;
      colv += e0 + e1;
    }
    FINCOL(S - 1)
#undef PROC
#undef FINCOL

    // batched col-sum write (skip diagonal tile J==I)
    __syncthreads();
    for (int idx = tid; idx < S * 32; idx += 128) {
      const int J = J0 + (idx >> 7);
      if (J != I)
        part[(size_t)I * MM + J * 128 + (idx & 127)] = colLds[0][idx] + colLds[1][idx];
    }

    // panel row-sums -> slot 100+q
#pragma unroll
    for (int m = 1; m < 32; m <<= 1)
#pragma unroll
      for (int r = 0; r < 16; ++r) {
        rAcc0[r] += __shfl_xor(rAcc0[r], m, 32);
        rAcc1[r] += __shfl_xor(rAcc1[r], m, 32);
      }
    if ((lane & 31) == 0) {
      const int rbase = I * 128 + wave * 64;
#pragma unroll
      for (int r = 0; r < 16; ++r) {
        const int rl = (r & 3) + 8 * (r >> 2) + 4 * lh2;
        part[(size_t)(NBLK + q) * MM + rbase + rl] = rAcc0[r];
        part[(size_t)(NBLK + q) * MM + rbase + 32 + rl] = rAcc1[r];
      }
    }
  } else {
    // ================= own/pos path (r9, validated) =================
    const int bid2 = blockIdx.x - NBLK * NCHUNK;
    const int c = bid2 >> 1, q2 = bid2 & 1;
    const int Ga = c * 8 + q2 * 4 + wave * 2;
    const int c8 = c * 8;

    bf16x8 A0[8], A1[8];
#pragma unroll
    for (int kc = 0; kc < 8; ++kc) {
      A0[kc] = *(const bf16x8*)(F + (size_t)Ga * 8192 + kc * 1024 + lo16);
      A1[kc] = *(const bf16x8*)(F + (size_t)(Ga + 1) * 8192 + kc * 1024 + lo16);
    }
    bf16x8 b0[8], b1[8];
    float rAcc0[16], rAcc1[16];
#pragma unroll
    for (int r = 0; r < 16; ++r) { rAcc0[r] = 0.f; rAcc1[r] = 0.f; }

#define OWNTILE(BB_) {                                                         \
    f32x16 a0 = MFMA32(A0[0], BB_[0], Z), a1 = MFMA32(A1[0], BB_[0], Z);       \
    _Pragma("unroll")                                                          \
    for (int kc = 1; kc < 8; ++kc) {                                           \
      a0 = MFMA32(A0[kc], BB_[kc], a0); a1 = MFMA32(A1[kc], BB_[kc], a1); }    \
    _Pragma("unroll")                                                          \
    for (int r = 0; r < 16; ++r) {                                             \
      rAcc0[r] += __builtin_amdgcn_exp2f(a0[r]);                               \
      rAcc1[r] += __builtin_amdgcn_exp2f(a1[r]); } }

#define REDUCEW(DST) {                                                         \
    float t0[16], t1[16];                                                      \
    _Pragma("unroll")                                                          \
    for (int r = 0; r < 16; ++r) { t0[r] = rAcc0[r]; t1[r] = rAcc1[r]; }       \
    _Pragma("unroll")                                                          \
    for (int m = 1; m < 32; m <<= 1)                                           \
      _Pragma("unroll")                                                        \
      for (int r = 0; r < 16; ++r) {                                           \
        t0[r] += __shfl_xor(t0[r], m, 32);                                     \
        t1[r] += __shfl_xor(t1[r], m, 32); }                                   \
    if ((lane & 31) == 0) {                                                    \
      const int rbase = c * 256 + q2 * 128 + wave * 64;                        \
      _Pragma("unroll")                                                        \
      for (int r = 0; r < 16; ++r) {                                           \
        const int rl = (r & 3) + 8 * (r >> 2) + 4 * lh2;                       \
        DST[rbase + rl] = t0[r];                                               \
        DST[rbase + 32 + rl] = t1[r]; } } }

    LOADB(b0, c8 + 0)
    LOADB(b1, c8 + 1)  OWNTILE(b0)
    LOADB(b0, c8 + 2)  OWNTILE(b1)
    LOADB(b1, c8 + 3)  OWNTILE(b0)
    LOADB(b0, c8 + 4)  OWNTILE(b1)
    REDUCEW(posArr)
    LOADB(b1, c8 + 5)  OWNTILE(b0)
    LOADB(b0, c8 + 6)  OWNTILE(b1)
    LOADB(b1, c8 + 7)  OWNTILE(b0)
    OWNTILE(b1)
    REDUCEW(ownArr)
#undef OWNTILE
#undef REDUCEW
  }
#undef LOADB
}

// ---------------------------------------------------------------------------
// Kernel 4: per-row loss + in-block reduction -> 50 partial sums.
// Sums exactly the slots written for this row-block:
//   col slots b = 0..pb-1  (neighbors' col-sums covering m-block b)
//   row slots 100+q for q with pb+8q <= 99 (this row's panel row-sums)
// ---------------------------------------------------------------------------
__global__ void finalize_rows(const float* __restrict__ part,
                              const float* __restrict__ ownArr,
                              const float* __restrict__ posArr,
                              float* __restrict__ partial) {
  __shared__ float red[4];
  const int t = threadIdx.x;
  const int p = blockIdx.x * 256 + t;
  const int pb = p >> 7;
  float a = 0.f;
  for (int b = 0; b < pb; ++b) a += part[(size_t)b * MM + p];
  const int qmax = (NBLK - 1 - pb) >> 3;
  for (int q = 0; q <= qmax; ++q) a += part[(size_t)(NBLK + q) * MM + p];
  float rl = logf(a - ownArr[p]) - logf(posArr[p]);
#pragma unroll
  for (int m = 1; m < 64; m <<= 1) rl += __shfl_xor(rl, m, 64);
  if ((t & 63) == 0) red[t >> 6] = rl;
  __syncthreads();
  if (t == 0) partial[blockIdx.x] = red[0] + red[1] + red[2] + red[3];
}

// ---------------------------------------------------------------------------
// Kernel 5: mean -> scalar
// ---------------------------------------------------------------------------
__global__ void final_reduce(const float* __restrict__ partial, float* __restrict__ out) {
  const int t = threadIdx.x;   // 64 threads
  float s = (t < MM / 256) ? partial[t] : 0.f;
#pragma unroll
  for (int m = 1; m < 64; m <<= 1) s += __shfl_xor(s, m, 64);
  if (t == 0) out[0] = s * (1.0f / MM);
}

extern "C" void kernel_launch(void* const* d_in, const int* in_sizes, int n_in,
                              void* d_out, int out_size, void* d_ws, size_t ws_size,
                              hipStream_t stream) {
  const float* prob = (const float*)d_in[0];
  const float* zi   = (const float*)d_in[1];
  const float* zj   = (const float*)d_in[2];
  float* out = (float*)d_out;

  char* ws = (char*)d_ws;
  char*  FT       = ws;                                  // 3,276,800 B
  float* part     = (float*)(ws + 3276800);              // 113*12800*4 = 5,785,600 B
  // cand buffers alias the (not-yet-live) part region: dead before sim writes.
  int*   candCnt  = (int*)  (ws + 3276800);              //    12,800 B
  int*   candIdx  = (int*)  (ws + 3276800 + 16384);      //   409,600 B
  float* candVal  = (float*)(ws + 3276800 + 430080);     //   409,600 B
  float* ownArr   = (float*)(ws + 9062400);              //    51,200 B
  float* posArr   = (float*)(ws + 9113600);              //    51,200 B
  float* partial  = (float*)(ws + 9164800);              //       256 B
  int*   topk     = (int*)  (ws + 9165056);              //    25,600 B -> end 9,190,656

  cand_kernel   <<<NPART, 256, 0, stream>>>(prob, candCnt, candIdx, candVal);
  select_kernel <<<CC, 256, 0, stream>>>(prob, candCnt, candIdx, candVal, topk);
  gather_norm   <<<MM / 4, 256, 0, stream>>>(zi, zj, topk, FT);
  sim_sym_kernel<<<NBLK * NCHUNK + 2 * CC, 128, 0, stream>>>(FT, part, ownArr, posArr);
  finalize_rows <<<MM / 256, 256, 0, stream>>>(part, ownArr, posArr, partial);
  final_reduce  <<<1, 64, 0, stream>>>(partial, out);
}